// Round 1
// baseline (150.398 us; speedup 1.0000x reference)
//
#include <hip/hip_runtime.h>
#include <math.h>

#define NN 1024
#define HH 64

typedef short bf16x8 __attribute__((ext_vector_type(8)));
typedef float f32x4 __attribute__((ext_vector_type(4)));

__device__ __forceinline__ unsigned short bf16_rne(float x) {
    unsigned int u = __float_as_uint(x);
    u += 0x7fffu + ((u >> 16) & 1u);
    return (unsigned short)(u >> 16);
}
__device__ __forceinline__ float bf16_up(unsigned short h) {
    return __uint_as_float(((unsigned int)h) << 16);
}

// ---- kernel 1: A'[n,h] = z_c[n,:]·W1c[:,h] + b1[h] ;  B[n,h] = z_d[n,:]·W1d[:,h]
// 512 blocks x 256 threads = 131072 = 2 * 1024 * 64
__global__ void prep_kernel(const float* __restrict__ z_c,
                            const float* __restrict__ z_d,
                            const float* __restrict__ W1,
                            const float* __restrict__ b1,
                            float* __restrict__ Ap,
                            float* __restrict__ Bp,
                            float* __restrict__ accum) {
    int t = blockIdx.x * blockDim.x + threadIdx.x;
    if (t == 0) { accum[0] = 0.0f; accum[1] = 0.0f; }  // runs before main (stream order)
    int sel = t >> 16;            // 0 -> A', 1 -> B
    int idx = t & 0xffff;
    int n = idx >> 6;
    int h = idx & 63;
    const float* z = (sel ? z_d : z_c) + n * 64;
    const float* w = W1 + (sel ? 64 * 64 : 0) + h;   // W1 is (128,64) row-major
    float acc = sel ? 0.0f : b1[h];
    #pragma unroll
    for (int k = 0; k < 64; ++k) acc = fmaf(z[k], w[k * 64], acc);
    (sel ? Bp : Ap)[idx] = acc;
}

// ---- kernel 2: one block per i. T1[i,j] for all j, online LSE; diagonal -> T0.
__global__ void __launch_bounds__(256)
main_kernel(const float* __restrict__ Ap, const float* __restrict__ Bp,
            const float* __restrict__ W2, const float* __restrict__ b2,
            const float* __restrict__ Wo, float* __restrict__ accum) {
    const int i    = blockIdx.x;
    const int lane = threadIdx.x & 63;
    const int wave = threadIdx.x >> 6;
    const int l15  = lane & 15;
    const int q    = lane >> 4;   // quad 0..3

    // W2 B-fragments (hi/lo split), resident in registers for the whole block.
    // B-layout for mfma_f32_16x16x32_bf16: lane holds B[k][n], n = lane&15, k = q*8+e.
    bf16x8 whi[2][4], wlo[2][4];
    #pragma unroll
    for (int s = 0; s < 2; ++s)
        #pragma unroll
        for (int t = 0; t < 4; ++t) {
            int n = t * 16 + l15;
            bf16x8 h, lo;
            #pragma unroll
            for (int e = 0; e < 8; ++e) {
                int k = s * 32 + q * 8 + e;
                float w = W2[k * 64 + n];
                unsigned short hb = bf16_rne(w);
                h[e]  = (short)hb;
                lo[e] = (short)bf16_rne(w - bf16_up(hb));
            }
            whi[s][t] = h; wlo[s][t] = lo;
        }

    // Per-lane slice of B[i,:] (the per-block bias for h1), k = s*32 + q*8 + e.
    float bb[2][8];
    #pragma unroll
    for (int s = 0; s < 2; ++s) {
        const float4* p = (const float4*)(Bp + i * 64 + s * 32 + q * 8);
        float4 v0 = p[0], v1 = p[1];
        bb[s][0] = v0.x; bb[s][1] = v0.y; bb[s][2] = v0.z; bb[s][3] = v0.w;
        bb[s][4] = v1.x; bb[s][5] = v1.y; bb[s][6] = v1.z; bb[s][7] = v1.w;
    }

    float b2v[4], wov[4];
    #pragma unroll
    for (int t = 0; t < 4; ++t) { b2v[t] = b2[t * 16 + l15]; wov[t] = Wo[t * 16 + l15]; }

    float mx = -INFINITY, se = 0.0f;
    const int jwbase = wave * 256;

    for (int tile = 0; tile < 16; ++tile) {
        const int jb   = jwbase + tile * 16;
        const int jrow = jb + l15;

        // Build h1 A-fragments directly in registers: A[m=l15][k=q*8+e]
        bf16x8 ahi[2], alo[2];
        #pragma unroll
        for (int s = 0; s < 2; ++s) {
            const float4* p = (const float4*)(Ap + jrow * 64 + s * 32 + q * 8);
            float4 v0 = p[0], v1 = p[1];
            float x[8] = {v0.x, v0.y, v0.z, v0.w, v1.x, v1.y, v1.z, v1.w};
            bf16x8 h, lo;
            #pragma unroll
            for (int e = 0; e < 8; ++e) {
                float val = fmaxf(x[e] + bb[s][e], 0.0f);   // h1 = relu(A' + B_i)
                unsigned short hb = bf16_rne(val);
                h[e]  = (short)hb;
                lo[e] = (short)bf16_rne(val - bf16_up(hb));
            }
            ahi[s] = h; alo[s] = lo;
        }

        f32x4 acc[4];
        #pragma unroll
        for (int t = 0; t < 4; ++t) acc[t] = (f32x4){0.0f, 0.0f, 0.0f, 0.0f};

        // h2pre = h1 @ W2, bf16x3 split (hi*hi + hi*lo + lo*hi), fp32 accumulate
        #pragma unroll
        for (int s = 0; s < 2; ++s)
            #pragma unroll
            for (int t = 0; t < 4; ++t) {
                acc[t] = __builtin_amdgcn_mfma_f32_16x16x32_bf16(ahi[s], whi[s][t], acc[t], 0, 0, 0);
                acc[t] = __builtin_amdgcn_mfma_f32_16x16x32_bf16(ahi[s], wlo[s][t], acc[t], 0, 0, 0);
                acc[t] = __builtin_amdgcn_mfma_f32_16x16x32_bf16(alo[s], whi[s][t], acc[t], 0, 0, 0);
            }

        // Epilogue: T1[i,j] = sum_n relu(h2pre + b2) * Wo.  C-layout: col=l15, row=q*4+r.
        #pragma unroll
        for (int r = 0; r < 4; ++r) {
            float sv = 0.0f;
            #pragma unroll
            for (int t = 0; t < 4; ++t)
                sv += fmaxf(acc[t][r] + b2v[t], 0.0f) * wov[t];
            #pragma unroll
            for (int off = 1; off < 16; off <<= 1) sv += __shfl_xor(sv, off);
            // sv = T1[i][j] (no bo; it cancels in the bound), replicated over l15
            int j = jb + q * 4 + r;
            if (j == i && l15 == 0) atomicAdd(&accum[0], sv);   // diagonal = T0[i]
            float nm = fmaxf(mx, sv);
            se = se * __expf(mx - nm) + __expf(sv - nm);
            mx = nm;
        }
    }

    // Wave butterfly LSE-combine (values replicated 16x across l15 -> se is 16x true sum)
    #pragma unroll
    for (int off = 1; off < 64; off <<= 1) {
        float om = __shfl_xor(mx, off);
        float os = __shfl_xor(se, off);
        float nm = fmaxf(mx, om);
        se = se * __expf(mx - nm) + os * __expf(om - nm);
        mx = nm;
    }
    __shared__ float smx[4], sse[4];
    if (lane == 0) { smx[wave] = mx; sse[wave] = se; }
    __syncthreads();
    if (threadIdx.x == 0) {
        float M = smx[0], S = sse[0];
        #pragma unroll
        for (int w = 1; w < 4; ++w) {
            float nm = fmaxf(M, smx[w]);
            S = S * __expf(M - nm) + sse[w] * __expf(smx[w] - nm);
            M = nm;
        }
        float lse = M + logf(S) - 2.7725887222397811f;  // - ln 16 (replication)
        atomicAdd(&accum[1], lse);
    }
}

// ---- kernel 3: bound = mean(T0) - (mean(LSE) - ln N)
__global__ void finish_kernel(const float* __restrict__ accum, float* __restrict__ out) {
    out[0] = accum[0] * (1.0f / NN) - (accum[1] * (1.0f / NN) - 6.9314718055994531f);
}

extern "C" void kernel_launch(void* const* d_in, const int* in_sizes, int n_in,
                              void* d_out, int out_size, void* d_ws, size_t ws_size,
                              hipStream_t stream) {
    const float* z_c = (const float*)d_in[0];
    const float* z_d = (const float*)d_in[1];
    const float* W1  = (const float*)d_in[2];
    const float* b1  = (const float*)d_in[3];
    const float* W2  = (const float*)d_in[4];
    const float* b2  = (const float*)d_in[5];
    const float* Wo  = (const float*)d_in[6];
    // d_in[7] = bo: shifts T0.mean and every LSE equally -> cancels exactly; omitted.
    float* out   = (float*)d_out;
    float* accum = (float*)d_ws;          // [0]=sum T0, [1]=sum LSE
    float* Ap    = accum + 16;            // N*64 floats (A' = z_c@W1c + b1)
    float* Bp    = Ap + NN * HH;          // N*64 floats (B  = z_d@W1d)
    // ws needed: 64 B + 2*256 KB = ~512 KB

    prep_kernel<<<512, 256, 0, stream>>>(z_c, z_d, W1, b1, Ap, Bp, accum);
    main_kernel<<<NN, 256, 0, stream>>>(Ap, Bp, W2, b2, Wo, accum);
    finish_kernel<<<1, 1, 0, stream>>>(accum, out);
}

// Round 2
// 124.052 us; speedup vs baseline: 1.2124x; 1.2124x over previous
//
#include <hip/hip_runtime.h>
#include <math.h>

#define NN 1024

typedef short bf16x8 __attribute__((ext_vector_type(8)));
typedef float f32x4 __attribute__((ext_vector_type(4)));

__device__ __forceinline__ unsigned rne_u(float x) {
    unsigned u = __float_as_uint(x);
    return u + 0x7fffu + ((u >> 16) & 1u);
}
__device__ __forceinline__ float bf16_up_bits(unsigned hi16) {
    return __uint_as_float(hi16 << 16);
}
// two fp32 -> one dword holding {bf16(a) lo, bf16(b) hi}, RNE
__device__ __forceinline__ unsigned pair_pack(float a, float b) {
    return (rne_u(a) >> 16) | (rne_u(b) & 0xffff0000u);
}

union U16 { uint4 u; bf16x8 v; };
union P4 { unsigned w[4]; bf16x8 v; };

// h1 A-fragment: relu(x + c), RNE to bf16, packed dwords (element e = pair order)
__device__ __forceinline__ bf16x8 mk_frag(float4 x0, float4 x1, float4 c0, float4 c1) {
    P4 u;
    u.w[0] = pair_pack(fmaxf(x0.x + c0.x, 0.f), fmaxf(x0.y + c0.y, 0.f));
    u.w[1] = pair_pack(fmaxf(x0.z + c0.z, 0.f), fmaxf(x0.w + c0.w, 0.f));
    u.w[2] = pair_pack(fmaxf(x1.x + c1.x, 0.f), fmaxf(x1.y + c1.y, 0.f));
    u.w[3] = pair_pack(fmaxf(x1.z + c1.z, 0.f), fmaxf(x1.w + c1.w, 0.f));
    return u.v;
}

// ---- prep: blocks [0,512): A'=z_c@W1c+b1, B=z_d@W1d (fp32 exact).
//            blocks [512,514): pack W2 into MFMA B-frag layout (hi+lo bf16 split),
//            zero Srow, zero accum.
__global__ void prep_kernel(const float* __restrict__ z_c, const float* __restrict__ z_d,
                            const float* __restrict__ W1, const float* __restrict__ b1,
                            const float* __restrict__ W2,
                            float* __restrict__ Ap, float* __restrict__ Bp,
                            uint4* __restrict__ W2hi, uint4* __restrict__ W2lo,
                            float* __restrict__ Srow, float* __restrict__ accum) {
    if (blockIdx.x < 512) {
        int t = blockIdx.x * 256 + threadIdx.x;
        if (t == 0) { accum[0] = 0.f; accum[1] = 0.f; }
        int sel = t >> 16;            // 0 -> A', 1 -> B
        int idx = t & 0xffff;
        int n = idx >> 6, h = idx & 63;
        const float* z = (sel ? z_d : z_c) + n * 64;
        const float* w = W1 + (sel ? 4096 : 0) + h;   // W1 (128,64) row-major
        float acc = sel ? 0.f : b1[h];
        #pragma unroll
        for (int k = 0; k < 64; ++k) acc = fmaf(z[k], w[k * 64], acc);
        (sel ? Bp : Ap)[idx] = acc;
    } else {
        int tt = (blockIdx.x - 512) * 256 + threadIdx.x;   // 0..511
        Srow[tt] = 0.f; Srow[tt + 512] = 0.f;
        int f = tt >> 6, lane = tt & 63;                   // f = s*4 + t (8 frags)
        int s = f >> 2, t4 = f & 3, q = lane >> 4, l15 = lane & 15;
        int n = t4 * 16 + l15;                             // B-frag: n = lane&15 (+16t)
        unsigned hi[4], lo[4];
        #pragma unroll
        for (int p = 0; p < 4; ++p) {
            int k = s * 32 + q * 8 + 2 * p;                // B-frag: k = quad*8 + e
            float w0 = W2[k * 64 + n], w1 = W2[(k + 1) * 64 + n];
            unsigned h0 = rne_u(w0) >> 16, h1 = rne_u(w1) >> 16;
            hi[p] = h0 | (h1 << 16);
            lo[p] = pair_pack(w0 - bf16_up_bits(h0), w1 - bf16_up_bits(h1));
        }
        W2hi[f * 64 + lane] = make_uint4(hi[0], hi[1], hi[2], hi[3]);
        W2lo[f * 64 + lane] = make_uint4(lo[0], lo[1], lo[2], lo[3]);
    }
}

// ---- main: block = (i, j-quarter). 4096 blocks x 256 thr; each wave 4 j-tiles of 16.
// T1[i,j] = relu(relu(A'_j + B_i) @ W2 + b2) . Wo   (bo dropped: cancels in bound)
// Accumulate sum_j exp(T1) into Srow[i] (atomic), diagonal T1[i,i] into accum[0].
__global__ void __launch_bounds__(256)
main_kernel(const float* __restrict__ Ap, const float* __restrict__ Bp,
            const uint4* __restrict__ W2hi, const uint4* __restrict__ W2lo,
            const float* __restrict__ b2, const float* __restrict__ Wo,
            float* __restrict__ Srow, float* __restrict__ accum) {
    const int i       = blockIdx.x >> 2;
    const int quarter = blockIdx.x & 3;
    const int lane = threadIdx.x & 63;
    const int wave = threadIdx.x >> 6;
    const int l15  = lane & 15;
    const int q    = lane >> 4;

    // W2 B-fragments: 16 coalesced dwordx4 loads (precomputed layout, L1/L2-hot)
    bf16x8 whi[2][4], wlo[2][4];
    #pragma unroll
    for (int f = 0; f < 8; ++f) {
        U16 a, b;
        a.u = W2hi[f * 64 + lane];
        b.u = W2lo[f * 64 + lane];
        whi[f >> 2][f & 3] = a.v;
        wlo[f >> 2][f & 3] = b.v;
    }

    // B_i slice per lane, k = s*32 + q*8 + e
    const float* bpr = Bp + i * 64 + q * 8;
    float4 c00 = *(const float4*)(bpr);
    float4 c01 = *(const float4*)(bpr + 4);
    float4 c10 = *(const float4*)(bpr + 32);
    float4 c11 = *(const float4*)(bpr + 36);

    float b2v[4], wov[4];
    #pragma unroll
    for (int t = 0; t < 4; ++t) { b2v[t] = b2[t * 16 + l15]; wov[t] = Wo[t * 16 + l15]; }

    const int jwbase = quarter * 256 + wave * 64;
    const float* ap = Ap + (jwbase + l15) * 64 + q * 8;
    // prefetch tile 0
    float4 x00 = *(const float4*)(ap);
    float4 x01 = *(const float4*)(ap + 4);
    float4 x10 = *(const float4*)(ap + 32);
    float4 x11 = *(const float4*)(ap + 36);

    float sacc = 0.f, t0acc = 0.f;

    #pragma unroll
    for (int tile = 0; tile < 4; ++tile) {
        bf16x8 a0 = mk_frag(x00, x01, c00, c01);   // s=0 (k 0..31)
        bf16x8 a1 = mk_frag(x10, x11, c10, c11);   // s=1 (k 32..63)
        if (tile < 3) {                             // prefetch next tile under MFMA+epilogue
            ap += 16 * 64;
            x00 = *(const float4*)(ap);
            x01 = *(const float4*)(ap + 4);
            x10 = *(const float4*)(ap + 32);
            x11 = *(const float4*)(ap + 36);
        }

        f32x4 acc[4];
        #pragma unroll
        for (int t = 0; t < 4; ++t) acc[t] = (f32x4){0.f, 0.f, 0.f, 0.f};
        // h2pre = h1 @ W2: A in bf16 (RNE, iid error -> averages out), W2 in hi+lo
        #pragma unroll
        for (int t = 0; t < 4; ++t) {
            acc[t] = __builtin_amdgcn_mfma_f32_16x16x32_bf16(a0, whi[0][t], acc[t], 0, 0, 0);
            acc[t] = __builtin_amdgcn_mfma_f32_16x16x32_bf16(a1, whi[1][t], acc[t], 0, 0, 0);
            acc[t] = __builtin_amdgcn_mfma_f32_16x16x32_bf16(a0, wlo[0][t], acc[t], 0, 0, 0);
            acc[t] = __builtin_amdgcn_mfma_f32_16x16x32_bf16(a1, wlo[1][t], acc[t], 0, 0, 0);
        }

        // epilogue: T1 = relu(acc + b2).Wo ; C-layout col=l15, row=q*4+r
        const int jb = jwbase + tile * 16 + q * 4;
        #pragma unroll
        for (int r = 0; r < 4; ++r) {
            float sv = 0.f;
            #pragma unroll
            for (int t = 0; t < 4; ++t)
                sv = fmaf(fmaxf(acc[t][r] + b2v[t], 0.f), wov[t], sv);
            sv += __shfl_xor(sv, 1);
            sv += __shfl_xor(sv, 2);
            sv += __shfl_xor(sv, 4);
            sv += __shfl_xor(sv, 8);
            // sv = T1[i][jb+r], replicated over the 16 l15 lanes
            t0acc += (jb + r == i) ? sv : 0.f;   // 16x-replicated; /16 in finish
            sacc  += __expf(sv);                  // no online max: |T1| small, fp32 safe
        }
    }

    #pragma unroll
    for (int off = 1; off < 64; off <<= 1) {
        sacc  += __shfl_xor(sacc, off);
        t0acc += __shfl_xor(t0acc, off);
    }
    __shared__ float sS[4], sT[4];
    if (lane == 0) { sS[wave] = sacc; sT[wave] = t0acc; }
    __syncthreads();
    if (threadIdx.x == 0) {
        float S = sS[0] + sS[1] + sS[2] + sS[3];   // 16 * sum_j exp(T1[i,j]) (partial)
        float T = sT[0] + sT[1] + sT[2] + sT[3];   // 16 * T0_i (or 0 if diag not here)
        atomicAdd(&Srow[i], S);
        if (T != 0.f) atomicAdd(&accum[0], T);     // adding 0 is a no-op: safe to skip
    }
}

// ---- combine: lse_i = log(Srow[i]/16), summed into accum[1]
__global__ void combine_kernel(const float* __restrict__ Srow, float* __restrict__ accum) {
    int i = blockIdx.x * 256 + threadIdx.x;
    float lse = logf(Srow[i] * 0.0625f);
    #pragma unroll
    for (int off = 1; off < 64; off <<= 1) lse += __shfl_xor(lse, off);
    if ((threadIdx.x & 63) == 0) atomicAdd(&accum[1], lse);
}

// ---- finish: bound = mean(T0) - (mean(lse) - ln N)
__global__ void finish_kernel(const float* __restrict__ accum, float* __restrict__ out) {
    out[0] = accum[0] * (1.0f / 16384.0f)
           - (accum[1] * (1.0f / 1024.0f) - 6.9314718055994531f);
}

extern "C" void kernel_launch(void* const* d_in, const int* in_sizes, int n_in,
                              void* d_out, int out_size, void* d_ws, size_t ws_size,
                              hipStream_t stream) {
    const float* z_c = (const float*)d_in[0];
    const float* z_d = (const float*)d_in[1];
    const float* W1  = (const float*)d_in[2];
    const float* b1  = (const float*)d_in[3];
    const float* W2  = (const float*)d_in[4];
    const float* b2  = (const float*)d_in[5];
    const float* Wo  = (const float*)d_in[6];
    // d_in[7] = bo: shifts T0.mean and every LSE equally -> cancels; omitted.
    float* out   = (float*)d_out;

    float* accum = (float*)d_ws;                 // [0]=16*sum T0, [1]=sum lse
    float* Ap    = accum + 16;                   // 65536 fp32
    float* Bp    = Ap + NN * 64;                 // 65536 fp32
    uint4* W2hi  = (uint4*)(Bp + NN * 64);       // 512 uint4 (8 KB)
    uint4* W2lo  = W2hi + 512;                   // 512 uint4 (8 KB)
    float* Srow  = (float*)(W2lo + 512);         // 1024 fp32
    // total ws use ~546 KB

    prep_kernel<<<514, 256, 0, stream>>>(z_c, z_d, W1, b1, W2, Ap, Bp, W2hi, W2lo, Srow, accum);
    main_kernel<<<4096, 256, 0, stream>>>(Ap, Bp, W2hi, W2lo, b2, Wo, Srow, accum);
    combine_kernel<<<4, 256, 0, stream>>>(Srow, accum);
    finish_kernel<<<1, 1, 0, stream>>>(accum, out);
}